// Round 4
// baseline (249.230 us; speedup 1.0000x reference)
//
#include <hip/hip_runtime.h>

typedef __attribute__((ext_vector_type(8))) __bf16 bf16x8;
typedef __attribute__((ext_vector_type(4))) __bf16 bf16x4;
typedef __attribute__((ext_vector_type(4))) float f32x4;
typedef __attribute__((ext_vector_type(16))) float f32x16;
typedef __attribute__((ext_vector_type(4))) unsigned int u32x4;

#define GLDS(g, l) __builtin_amdgcn_global_load_lds( \
    (const __attribute__((address_space(1))) void*)(g), \
    (__attribute__((address_space(3))) void*)(l), 16, 0, 0)

__device__ __forceinline__ unsigned cvtpk_bf16(float lo, float hi) {
    unsigned r;
    asm("v_cvt_pk_bf16_f32 %0, %1, %2" : "=v"(r) : "v"(lo), "v"(hi));
    return r;
}
__device__ __forceinline__ void pl32swap(unsigned& a, unsigned& b) {
    asm("v_permlane32_swap_b32 %0, %1" : "+v"(a), "+v"(b));
}

// ---- fp32 [8192][1024] -> tiled bf16 A-layout [mt][ks][chunk4][row128][8] ----
__global__ __launch_bounds__(256) void cvt_tile(const float* __restrict__ q,
                                                const float* __restrict__ k,
                                                const float* __restrict__ v,
                                                __bf16* __restrict__ qo,
                                                __bf16* __restrict__ ko,
                                                __bf16* __restrict__ vo) {
    const float* src = blockIdx.z == 0 ? q : blockIdx.z == 1 ? k : v;
    __bf16* dst = blockIdx.z == 0 ? qo : blockIdx.z == 1 ? ko : vo;
    __shared__ __align__(16) __bf16 sb[128 * 64];
    const int t = threadIdx.x;
    const int m0 = blockIdx.x * 128, kk0 = blockIdx.y * 64;
    #pragma unroll
    for (int i = 0; i < 4; i++) {
        int cid = i * 256 + t;
        int r = cid >> 3, cc = cid & 7;
        const float* p = src + (size_t)(m0 + r) * 1024 + kk0 + cc * 8;
        float4 a = *(const float4*)p;
        float4 b2 = *(const float4*)(p + 4);
        bf16x8 o;
        o[0] = (__bf16)a.x;  o[1] = (__bf16)a.y;  o[2] = (__bf16)a.z;  o[3] = (__bf16)a.w;
        o[4] = (__bf16)b2.x; o[5] = (__bf16)b2.y; o[6] = (__bf16)b2.z; o[7] = (__bf16)b2.w;
        *(bf16x8*)((char*)sb + r * 128 + ((cc ^ (r & 7)) << 4)) = o;
    }
    __syncthreads();
    #pragma unroll
    for (int i = 0; i < 4; i++) {
        int cid = i * 256 + t;
        int ch = cid >> 7, r = cid & 127;
        bf16x8 o = *(const bf16x8*)((const char*)sb + r * 128 + ((ch ^ (r & 7)) << 4));
        size_t off = (((size_t)blockIdx.x * 32 + blockIdx.y * 2 + (ch >> 2)) * 4 + (ch & 3)) * 1024
                   + (size_t)r * 8;
        *(bf16x8*)(dst + off) = o;
    }
}

// ---- W [K][N] f32 -> tiled bf16 B-layout [nt][ks][chunk4][row128][8] ----
__global__ __launch_bounds__(256) void wtrans2(const float* __restrict__ W,
                                               __bf16* __restrict__ Wt2) {
    __shared__ float lw[64][65];
    const int kt = blockIdx.y * 64, nt = blockIdx.x * 64;
    const int t = threadIdx.x;
    const int r = t >> 4;
    const int c4 = (t & 15) * 4;
    #pragma unroll
    for (int rr = 0; rr < 64; rr += 16) {
        float4 vv = *(const float4*)&W[(size_t)(kt + r + rr) * 1024 + nt + c4];
        lw[r + rr][c4 + 0] = vv.x; lw[r + rr][c4 + 1] = vv.y;
        lw[r + rr][c4 + 2] = vv.z; lw[r + rr][c4 + 3] = vv.w;
    }
    __syncthreads();
    #pragma unroll
    for (int rr = 0; rr < 64; rr += 16) {
        int n = nt + r + rr;
        bf16x4 ov;
        #pragma unroll
        for (int i = 0; i < 4; i++) ov[i] = (__bf16)lw[c4 + i][r + rr];
        int kg = kt + c4;
        size_t off = (((size_t)(n >> 7) * 32 + (kg >> 5)) * 4 + ((kg & 31) >> 3)) * 1024
                   + (size_t)(n & 127) * 8 + (kg & 7);
        *(bf16x4*)&Wt2[off] = ov;
    }
}

// ---- GEMM 256x128 tile, 8 waves, 3-buffer counted-vmcnt pipeline ----
// mode: 0=f32 row-major, 1=bf16 row-major scaled (Q), 2=K-tiled, 3=V-tiled
__global__ __launch_bounds__(512, 2)
void gemm_tt(const __bf16* __restrict__ A0, const __bf16* __restrict__ A1,
             const __bf16* __restrict__ A2,
             const __bf16* __restrict__ B0, const __bf16* __restrict__ B1,
             const __bf16* __restrict__ B2,
             const float* __restrict__ bi0, const float* __restrict__ bi1,
             const float* __restrict__ bi2,
             void* __restrict__ C0, void* __restrict__ C1, void* __restrict__ C2,
             int mode0) {
    __shared__ __align__(16) __bf16 sA[3 * 8192];
    __shared__ __align__(16) __bf16 sB[3 * 4096];
    const int y = blockIdx.y;
    const __bf16* At  = y == 0 ? A0 : y == 1 ? A1 : A2;
    const __bf16* Bt2 = y == 0 ? B0 : y == 1 ? B1 : B2;
    const float* bias = y == 0 ? bi0 : y == 1 ? bi1 : bi2;
    void* Cout        = y == 0 ? C0 : y == 1 ? C1 : C2;
    const int mode    = y == 0 ? mode0 : y + 1;

    const int t = threadIdx.x, l = t & 63, w = t >> 6;
    const int wr = w >> 1, wc = w & 1;
    const int bid = blockIdx.x;
    const int ytile = (bid & 7) * 4 + ((bid >> 3) & 3);   // 0..31, XCD-contiguous
    const int xtile = bid >> 5;                           // 0..7
    const __bf16* Ab = At + (size_t)ytile * 262144;
    const __bf16* Bb = Bt2 + (size_t)xtile * 131072;

#define GISSUE(ks_, buf_) do { \
    GLDS(Ab + (ks_) * 4096 + t * 8,          (char*)sA + (buf_) * 16384 + t * 16); \
    GLDS(Ab + 131072 + (ks_) * 4096 + t * 8, (char*)sA + (buf_) * 16384 + 8192 + t * 16); \
    GLDS(Bb + (ks_) * 4096 + t * 8,          (char*)sB + (buf_) * 8192 + t * 16); \
} while (0)

    f32x4 acc[4][4];
    #pragma unroll
    for (int i = 0; i < 4; i++)
        #pragma unroll
        for (int j = 0; j < 4; j++) acc[i][j] = (f32x4){0.f, 0.f, 0.f, 0.f};

    GISSUE(0, 0);
    GISSUE(1, 1);
    int cur = 0;
    #pragma unroll 1
    for (int ks = 0; ks < 32; ++ks) {
        if (ks < 31) asm volatile("s_waitcnt vmcnt(3)" ::: "memory");
        else         asm volatile("s_waitcnt vmcnt(0)" ::: "memory");
        __builtin_amdgcn_s_barrier();
        __builtin_amdgcn_sched_barrier(0);
        if (ks + 2 < 32) GISSUE(ks + 2, cur >= 1 ? cur - 1 : 2);
        const __bf16* bA = sA + cur * 8192;
        const __bf16* bB = sB + cur * 4096;
        bf16x8 af[4], bfr[4];
        #pragma unroll
        for (int i = 0; i < 4; i++)
            af[i] = *(const bf16x8*)(bA + (wr >> 1) * 4096 + (l >> 4) * 1024
                                        + ((wr & 1) * 64 + i * 16 + (l & 15)) * 8);
        #pragma unroll
        for (int j = 0; j < 4; j++)
            bfr[j] = *(const bf16x8*)(bB + (l >> 4) * 1024 + (wc * 64 + j * 16 + (l & 15)) * 8);
        __builtin_amdgcn_s_setprio(1);
        #pragma unroll
        for (int i = 0; i < 4; i++)
            #pragma unroll
            for (int j = 0; j < 4; j++)
                acc[i][j] = __builtin_amdgcn_mfma_f32_16x16x32_bf16(af[i], bfr[j], acc[i][j], 0, 0, 0);
        __builtin_amdgcn_s_setprio(0);
        cur = cur == 2 ? 0 : cur + 1;
    }
#undef GISSUE

    const int m0 = ytile * 256, n0 = xtile * 128;
    #pragma unroll
    for (int j = 0; j < 4; j++) {
        int col = n0 + wc * 64 + j * 16 + (l & 15);
        float bv = bias[col];
        #pragma unroll
        for (int i = 0; i < 4; i++) {
            #pragma unroll
            for (int r = 0; r < 4; r++) {
                int row = m0 + wr * 64 + i * 16 + (l >> 4) * 4 + r;
                float vvv = acc[i][j][r] + bv;
                if (mode == 0) {
                    ((float*)Cout)[(size_t)row * 1024 + col] = vvv;
                } else if (mode == 1) {
                    ((__bf16*)Cout)[(size_t)row * 1024 + col] = (__bf16)(vvv * 0.18033688f);
                } else if (mode == 2) {
                    int b_ = row >> 11, s_ = row & 2047, h_ = col >> 6, hd_ = col & 63;
                    size_t off = ((size_t)(b_ * 16 + h_) * 32 + (s_ >> 6)) * 4096
                               + (size_t)(hd_ >> 3) * 512 + (s_ & 63) * 8 + (hd_ & 7);
                    ((__bf16*)Cout)[off] = (__bf16)vvv;
                } else {
                    int b_ = row >> 11, s_ = row & 2047, h_ = col >> 6, d_ = col & 63;
                    size_t off = ((size_t)(b_ * 16 + h_) * 32 + (s_ >> 6)) * 4096
                               + (size_t)((s_ & 63) >> 3) * 512 + (size_t)d_ * 8 + (s_ & 7);
                    ((__bf16*)Cout)[off] = (__bf16)vvv;
                }
            }
        }
    }
}

// ---- Flash attention v4: ones-MFMA row sums, setprio, 3-buffer pipeline ----
__global__ __launch_bounds__(256, 2)
void attn_fwd(const __bf16* __restrict__ Qp, const __bf16* __restrict__ Kt,
              const __bf16* __restrict__ Vtt, __bf16* __restrict__ AOt) {
    constexpr int S = 2048, D = 1024;
    __shared__ __align__(16) __bf16 sK[3 * 4096];
    __shared__ __align__(16) __bf16 sV[3 * 4096];
    const int t = threadIdx.x, l = t & 63, w = t >> 6;
    const int c = l & 31, g = l >> 5;
    const int bid = blockIdx.x, slot = bid >> 3;
    const int bh = (slot >> 3) * 8 + (bid & 7);     // bh % 8 == XCD
    const int qb = slot & 7;
    const int b = bh >> 4, h = bh & 15;
    const int q0 = qb * 256;
    const __bf16* Kb = Kt + (size_t)bh * 131072;
    const __bf16* Vb = Vtt + (size_t)bh * 131072;

    // Q B-fragments: rows q0 + w*64 + qh*32 + c, dims ks*16 + g*8
    bf16x8 qf[2][4];
    #pragma unroll
    for (int qh = 0; qh < 2; qh++) {
        const __bf16* qp = Qp + (size_t)(b * S + q0 + w * 64 + qh * 32 + c) * D + h * 64;
        #pragma unroll
        for (int ks = 0; ks < 4; ks++)
            qf[qh][ks] = *(const bf16x8*)(qp + ks * 16 + g * 8);
    }
    const __bf16 one = (__bf16)1.0f;
    const bf16x8 ones = {one, one, one, one, one, one, one, one};
    asm volatile("s_waitcnt vmcnt(0)" ::: "memory");   // clean vmcnt before pipeline

#define AISSUE(ti_, buf_) do { \
    GLDS(Kb + (ti_) * 4096 + t * 8,        (char*)sK + (buf_) * 8192 + t * 16); \
    GLDS(Kb + (ti_) * 4096 + 2048 + t * 8, (char*)sK + (buf_) * 8192 + 4096 + t * 16); \
    GLDS(Vb + (ti_) * 4096 + t * 8,        (char*)sV + (buf_) * 8192 + t * 16); \
    GLDS(Vb + (ti_) * 4096 + 2048 + t * 8, (char*)sV + (buf_) * 8192 + 4096 + t * 16); \
} while (0)

    f32x16 acc[2][2];
    acc[0][0] = (f32x16){}; acc[0][1] = (f32x16){};
    acc[1][0] = (f32x16){}; acc[1][1] = (f32x16){};
    f32x16 accl[2];
    accl[0] = (f32x16){}; accl[1] = (f32x16){};

    AISSUE(0, 0);
    AISSUE(1, 1);
    int cur = 0;
    #pragma unroll 1
    for (int tile = 0; tile < 32; ++tile) {
        if (tile < 31) asm volatile("s_waitcnt vmcnt(4)" ::: "memory");
        else           asm volatile("s_waitcnt vmcnt(0)" ::: "memory");
        __builtin_amdgcn_s_barrier();
        __builtin_amdgcn_sched_barrier(0);
        if (tile + 2 < 32) AISSUE(tile + 2, cur >= 1 ? cur - 1 : 2);
        const __bf16* bK = sK + cur * 4096;
        const __bf16* bV = sV + cur * 4096;
        #pragma unroll
        for (int kt = 0; kt < 2; kt++) {
            bf16x8 kf[4];
            #pragma unroll
            for (int ks = 0; ks < 4; ks++)
                kf[ks] = *(const bf16x8*)(bK + ((2 * ks + g) * 64 + kt * 32 + c) * 8);
            bf16x8 vq0[2], vq1[2];
            #pragma unroll
            for (int ti = 0; ti < 2; ti++) {
                vq0[ti] = *(const bf16x8*)(bV + ((4 * kt + g) * 64 + ti * 32 + c) * 8);
                vq1[ti] = *(const bf16x8*)(bV + ((4 * kt + 2 + g) * 64 + ti * 32 + c) * 8);
            }
            #pragma unroll
            for (int qh = 0; qh < 2; qh++) {
                f32x16 St = {};
                __builtin_amdgcn_s_setprio(1);
                St = __builtin_amdgcn_mfma_f32_32x32x16_bf16(kf[0], qf[qh][0], St, 0, 0, 0);
                St = __builtin_amdgcn_mfma_f32_32x32x16_bf16(kf[1], qf[qh][1], St, 0, 0, 0);
                St = __builtin_amdgcn_mfma_f32_32x32x16_bf16(kf[2], qf[qh][2], St, 0, 0, 0);
                St = __builtin_amdgcn_mfma_f32_32x32x16_bf16(kf[3], qf[qh][3], St, 0, 0, 0);
                __builtin_amdgcn_s_setprio(0);
                #pragma unroll
                for (int r2 = 0; r2 < 16; r2++)
                    St[r2] = __builtin_amdgcn_exp2f(St[r2]);
                unsigned w0 = cvtpk_bf16(St[0], St[1]),   w1 = cvtpk_bf16(St[2], St[3]);
                unsigned w2 = cvtpk_bf16(St[4], St[5]),   w3 = cvtpk_bf16(St[6], St[7]);
                unsigned w4 = cvtpk_bf16(St[8], St[9]),   w5 = cvtpk_bf16(St[10], St[11]);
                unsigned w6 = cvtpk_bf16(St[12], St[13]), w7 = cvtpk_bf16(St[14], St[15]);
                pl32swap(w0, w2); pl32swap(w1, w3);
                pl32swap(w4, w6); pl32swap(w5, w7);
                bf16x8 pa0 = __builtin_bit_cast(bf16x8, (u32x4){w0, w1, w2, w3});
                bf16x8 pa1 = __builtin_bit_cast(bf16x8, (u32x4){w4, w5, w6, w7});
                __builtin_amdgcn_s_setprio(1);
                acc[qh][0] = __builtin_amdgcn_mfma_f32_32x32x16_bf16(pa0, vq0[0], acc[qh][0], 0, 0, 0);
                acc[qh][1] = __builtin_amdgcn_mfma_f32_32x32x16_bf16(pa0, vq0[1], acc[qh][1], 0, 0, 0);
                acc[qh][0] = __builtin_amdgcn_mfma_f32_32x32x16_bf16(pa1, vq1[0], acc[qh][0], 0, 0, 0);
                acc[qh][1] = __builtin_amdgcn_mfma_f32_32x32x16_bf16(pa1, vq1[1], acc[qh][1], 0, 0, 0);
                accl[qh] = __builtin_amdgcn_mfma_f32_32x32x16_bf16(pa0, ones, accl[qh], 0, 0, 0);
                accl[qh] = __builtin_amdgcn_mfma_f32_32x32x16_bf16(pa1, ones, accl[qh], 0, 0, 0);
                __builtin_amdgcn_s_setprio(0);
            }
        }
        cur = cur == 2 ? 0 : cur + 1;
    }
#undef AISSUE

    // write O in tiled-A layout for the final GEMM: m = b*2048+q, k = h*64 + ti*32 + c
    #pragma unroll
    for (int qh = 0; qh < 2; qh++)
        #pragma unroll
        for (int rq = 0; rq < 4; rq++)
            #pragma unroll
            for (int rr2 = 0; rr2 < 4; rr2++) {
                int reg = rq * 4 + rr2;
                int rloc = rr2 + 8 * rq + 4 * g;
                float rn = __builtin_amdgcn_rcpf(accl[qh][reg]);
                int qloc = w * 64 + qh * 32 + rloc;
                int mt = b * 16 + qb * 2 + (qloc >> 7);
                int mr = qloc & 127;
                size_t base = ((size_t)mt * 32 + h * 2) * 4096 + (size_t)(c >> 3) * 1024
                            + (size_t)mr * 8 + (c & 7);
                AOt[base] = (__bf16)(acc[qh][0][reg] * rn);
                AOt[base + 4096] = (__bf16)(acc[qh][1][reg] * rn);
            }
}

extern "C" void kernel_launch(void* const* d_in, const int* in_sizes, int n_in,
                              void* d_out, int out_size, void* d_ws, size_t ws_size,
                              hipStream_t stream) {
    const float* q  = (const float*)d_in[0];
    const float* k  = (const float*)d_in[1];
    const float* v  = (const float*)d_in[2];
    const float* Wq = (const float*)d_in[3];
    const float* bq = (const float*)d_in[4];
    const float* Wk = (const float*)d_in[5];
    const float* bk = (const float*)d_in[6];
    const float* Wv = (const float*)d_in[7];
    const float* bv = (const float*)d_in[8];
    const float* Wo = (const float*)d_in[9];
    const float* bo = (const float*)d_in[10];

    char* ws = (char*)d_ws;
    const size_t MiB = 1024 * 1024;
    __bf16* Atq = (__bf16*)(ws);             // tiled bf16 q (16MB); later reused as AOt
    __bf16* Atk = (__bf16*)(ws + 16 * MiB);
    __bf16* Atv = (__bf16*)(ws + 32 * MiB);
    __bf16* W2q = (__bf16*)(ws + 48 * MiB);
    __bf16* W2k = (__bf16*)(ws + 50 * MiB);
    __bf16* W2v = (__bf16*)(ws + 52 * MiB);
    __bf16* W2o = (__bf16*)(ws + 54 * MiB);
    __bf16* Qp  = (__bf16*)(ws + 56 * MiB);  // row-major bf16, pre-scaled
    __bf16* Kt  = (__bf16*)(ws + 72 * MiB);  // K tiled
    __bf16* Vtt = (__bf16*)(ws + 88 * MiB);  // V tiled
    __bf16* AOt = (__bf16*)(ws);             // attn out, tiled A (aliases Atq, dead)

    cvt_tile<<<dim3(64, 16, 3), 256, 0, stream>>>(q, k, v, Atq, Atk, Atv);

    dim3 wg(16, 16);
    wtrans2<<<wg, 256, 0, stream>>>(Wq, W2q);
    wtrans2<<<wg, 256, 0, stream>>>(Wk, W2k);
    wtrans2<<<wg, 256, 0, stream>>>(Wv, W2v);
    wtrans2<<<wg, 256, 0, stream>>>(Wo, W2o);

    // merged Q/K/V projection GEMMs (grid.y selects operand set; modes 1,2,3)
    gemm_tt<<<dim3(256, 3), 512, 0, stream>>>(Atq, Atk, Atv, W2q, W2k, W2v,
                                              bq, bk, bv, Qp, Kt, Vtt, 1);

    attn_fwd<<<512, 256, 0, stream>>>(Qp, Kt, Vtt, AOt);

    // output projection (mode 0: f32 row-major to d_out)
    gemm_tt<<<dim3(256, 1), 512, 0, stream>>>(AOt, AOt, AOt, W2o, W2o, W2o,
                                              bo, bo, bo, d_out, d_out, d_out, 0);
}

// Round 5
// 205.897 us; speedup vs baseline: 1.2105x; 1.2105x over previous
//
#include <hip/hip_runtime.h>

typedef __attribute__((ext_vector_type(8))) __bf16 bf16x8;
typedef __attribute__((ext_vector_type(4))) __bf16 bf16x4;
typedef __attribute__((ext_vector_type(4))) float f32x4;
typedef __attribute__((ext_vector_type(16))) float f32x16;
typedef __attribute__((ext_vector_type(4))) unsigned int u32x4;

#define GLDS(g, l) __builtin_amdgcn_global_load_lds( \
    (const __attribute__((address_space(1))) void*)(g), \
    (__attribute__((address_space(3))) void*)(l), 16, 0, 0)

__device__ __forceinline__ unsigned cvtpk_bf16(float lo, float hi) {
    unsigned r;
    asm("v_cvt_pk_bf16_f32 %0, %1, %2" : "=v"(r) : "v"(lo), "v"(hi));
    return r;
}
__device__ __forceinline__ void pl32swap(unsigned& a, unsigned& b) {
    asm("v_permlane32_swap_b32 %0, %1" : "+v"(a), "+v"(b));
}

// ---- fp32 [8192][1024] -> tiled bf16 A-layout [mt][ks][chunk4][row128][8] ----
__global__ __launch_bounds__(256) void cvt_tile(const float* __restrict__ q,
                                                const float* __restrict__ k,
                                                const float* __restrict__ v,
                                                __bf16* __restrict__ qo,
                                                __bf16* __restrict__ ko,
                                                __bf16* __restrict__ vo) {
    const float* src = blockIdx.z == 0 ? q : blockIdx.z == 1 ? k : v;
    __bf16* dst = blockIdx.z == 0 ? qo : blockIdx.z == 1 ? ko : vo;
    __shared__ __align__(16) __bf16 sb[128 * 64];
    const int t = threadIdx.x;
    const int m0 = blockIdx.x * 128, kk0 = blockIdx.y * 64;
    #pragma unroll
    for (int i = 0; i < 4; i++) {
        int cid = i * 256 + t;
        int r = cid >> 3, cc = cid & 7;
        const float* p = src + (size_t)(m0 + r) * 1024 + kk0 + cc * 8;
        float4 a = *(const float4*)p;
        float4 b2 = *(const float4*)(p + 4);
        bf16x8 o;
        o[0] = (__bf16)a.x;  o[1] = (__bf16)a.y;  o[2] = (__bf16)a.z;  o[3] = (__bf16)a.w;
        o[4] = (__bf16)b2.x; o[5] = (__bf16)b2.y; o[6] = (__bf16)b2.z; o[7] = (__bf16)b2.w;
        *(bf16x8*)((char*)sb + r * 128 + ((cc ^ (r & 7)) << 4)) = o;
    }
    __syncthreads();
    #pragma unroll
    for (int i = 0; i < 4; i++) {
        int cid = i * 256 + t;
        int ch = cid >> 7, r = cid & 127;
        bf16x8 o = *(const bf16x8*)((const char*)sb + r * 128 + ((ch ^ (r & 7)) << 4));
        size_t off = (((size_t)blockIdx.x * 32 + blockIdx.y * 2 + (ch >> 2)) * 4 + (ch & 3)) * 1024
                   + (size_t)r * 8;
        *(bf16x8*)(dst + off) = o;
    }
}

// ---- W [K][N] f32 -> tiled bf16 B-layout [nt][ks][chunk4][row128][8] ----
__global__ __launch_bounds__(256) void wtrans2(const float* __restrict__ W0,
                                               const float* __restrict__ W1,
                                               const float* __restrict__ W2,
                                               const float* __restrict__ W3,
                                               __bf16* __restrict__ O0,
                                               __bf16* __restrict__ O1,
                                               __bf16* __restrict__ O2,
                                               __bf16* __restrict__ O3) {
    const int z = blockIdx.z;
    const float* W = z == 0 ? W0 : z == 1 ? W1 : z == 2 ? W2 : W3;
    __bf16* Wt2 = z == 0 ? O0 : z == 1 ? O1 : z == 2 ? O2 : O3;
    __shared__ float lw[64][65];
    const int kt = blockIdx.y * 64, nt = blockIdx.x * 64;
    const int t = threadIdx.x;
    const int r = t >> 4;
    const int c4 = (t & 15) * 4;
    #pragma unroll
    for (int rr = 0; rr < 64; rr += 16) {
        float4 vv = *(const float4*)&W[(size_t)(kt + r + rr) * 1024 + nt + c4];
        lw[r + rr][c4 + 0] = vv.x; lw[r + rr][c4 + 1] = vv.y;
        lw[r + rr][c4 + 2] = vv.z; lw[r + rr][c4 + 3] = vv.w;
    }
    __syncthreads();
    #pragma unroll
    for (int rr = 0; rr < 64; rr += 16) {
        int n = nt + r + rr;
        bf16x4 ov;
        #pragma unroll
        for (int i = 0; i < 4; i++) ov[i] = (__bf16)lw[c4 + i][r + rr];
        int kg = kt + c4;
        size_t off = (((size_t)(n >> 7) * 32 + (kg >> 5)) * 4 + ((kg & 31) >> 3)) * 1024
                   + (size_t)(n & 127) * 8 + (kg & 7);
        *(bf16x4*)&Wt2[off] = ov;
    }
}

// ---- GEMM 128x128, 4 waves, 3-buffer counted-vmcnt pipeline (round-3 core) ----
// mode: 0=f32 row-major, 1=bf16 row-major scaled (Q), 2=K-tiled, 3=V-tiled
__global__ __launch_bounds__(256, 2)
void gemm_tt(const __bf16* __restrict__ A0, const __bf16* __restrict__ A1,
             const __bf16* __restrict__ A2,
             const __bf16* __restrict__ B0, const __bf16* __restrict__ B1,
             const __bf16* __restrict__ B2,
             const float* __restrict__ bi0, const float* __restrict__ bi1,
             const float* __restrict__ bi2,
             void* __restrict__ C0, void* __restrict__ C1, void* __restrict__ C2,
             int mode0) {
    __shared__ __align__(16) __bf16 sA[3 * 4096];
    __shared__ __align__(16) __bf16 sB[3 * 4096];
    const int y = blockIdx.y;
    const __bf16* At  = y == 0 ? A0 : y == 1 ? A1 : A2;
    const __bf16* Bt2 = y == 0 ? B0 : y == 1 ? B1 : B2;
    const float* bias = y == 0 ? bi0 : y == 1 ? bi1 : bi2;
    void* Cout        = y == 0 ? C0 : y == 1 ? C1 : C2;
    const int mode    = y == 0 ? mode0 : y + 1;

    const int t = threadIdx.x, l = t & 63, w = t >> 6;
    const int wr = w >> 1, wc = w & 1;
    const int bid = blockIdx.x, slot = bid >> 3;
    const int ytile = (bid & 7) * 8 + (slot & 7);   // XCD-contiguous M-stripes
    const int xtile = slot >> 3;
    const __bf16* Ab = At + (size_t)ytile * 131072;
    const __bf16* Bb = Bt2 + (size_t)xtile * 131072;

#define GISSUE(ks_, buf_) do { \
    GLDS(Ab + (ks_) * 4096 + t * 8,        (char*)sA + (buf_) * 8192 + t * 16); \
    GLDS(Ab + (ks_) * 4096 + 2048 + t * 8, (char*)sA + (buf_) * 8192 + 4096 + t * 16); \
    GLDS(Bb + (ks_) * 4096 + t * 8,        (char*)sB + (buf_) * 8192 + t * 16); \
    GLDS(Bb + (ks_) * 4096 + 2048 + t * 8, (char*)sB + (buf_) * 8192 + 4096 + t * 16); \
} while (0)

    f32x4 acc[4][4];
    #pragma unroll
    for (int i = 0; i < 4; i++)
        #pragma unroll
        for (int j = 0; j < 4; j++) acc[i][j] = (f32x4){0.f, 0.f, 0.f, 0.f};

    GISSUE(0, 0);
    GISSUE(1, 1);
    int cur = 0;
    #pragma unroll 1
    for (int ks = 0; ks < 32; ++ks) {
        if (ks < 31) asm volatile("s_waitcnt vmcnt(4)" ::: "memory");
        else         asm volatile("s_waitcnt vmcnt(0)" ::: "memory");
        __builtin_amdgcn_s_barrier();
        __builtin_amdgcn_sched_barrier(0);
        if (ks + 2 < 32) GISSUE(ks + 2, cur >= 1 ? cur - 1 : 2);
        const __bf16* bA = sA + cur * 4096;
        const __bf16* bB = sB + cur * 4096;
        bf16x8 af[4], bfr[4];
        #pragma unroll
        for (int i = 0; i < 4; i++)
            af[i] = *(const bf16x8*)(bA + (l >> 4) * 1024 + (wr * 64 + i * 16 + (l & 15)) * 8);
        #pragma unroll
        for (int j = 0; j < 4; j++)
            bfr[j] = *(const bf16x8*)(bB + (l >> 4) * 1024 + (wc * 64 + j * 16 + (l & 15)) * 8);
        __builtin_amdgcn_s_setprio(1);
        #pragma unroll
        for (int i = 0; i < 4; i++)
            #pragma unroll
            for (int j = 0; j < 4; j++)
                acc[i][j] = __builtin_amdgcn_mfma_f32_16x16x32_bf16(af[i], bfr[j], acc[i][j], 0, 0, 0);
        __builtin_amdgcn_s_setprio(0);
        cur = cur == 2 ? 0 : cur + 1;
    }
#undef GISSUE

    const int m0 = ytile * 128, n0 = xtile * 128;
    #pragma unroll
    for (int j = 0; j < 4; j++) {
        int col = n0 + wc * 64 + j * 16 + (l & 15);
        float bv = bias[col];
        #pragma unroll
        for (int i = 0; i < 4; i++) {
            #pragma unroll
            for (int r = 0; r < 4; r++) {
                int row = m0 + wr * 64 + i * 16 + (l >> 4) * 4 + r;
                float vvv = acc[i][j][r] + bv;
                if (mode == 0) {
                    ((float*)Cout)[(size_t)row * 1024 + col] = vvv;
                } else if (mode == 1) {
                    ((__bf16*)Cout)[(size_t)row * 1024 + col] = (__bf16)(vvv * 0.18033688f);
                } else if (mode == 2) {
                    int b_ = row >> 11, s_ = row & 2047, h_ = col >> 6, hd_ = col & 63;
                    size_t off = ((size_t)(b_ * 16 + h_) * 32 + (s_ >> 6)) * 4096
                               + (size_t)(hd_ >> 3) * 512 + (s_ & 63) * 8 + (hd_ & 7);
                    ((__bf16*)Cout)[off] = (__bf16)vvv;
                } else {
                    int b_ = row >> 11, s_ = row & 2047, h_ = col >> 6, d_ = col & 63;
                    size_t off = ((size_t)(b_ * 16 + h_) * 32 + (s_ >> 6)) * 4096
                               + (size_t)((s_ & 63) >> 3) * 512 + (size_t)d_ * 8 + (s_ & 7);
                    ((__bf16*)Cout)[off] = (__bf16)vvv;
                }
            }
        }
    }
}

// ---- Flash attention v4: ones-MFMA row sums, setprio, 3-buffer pipeline ----
__global__ __launch_bounds__(256, 2)
void attn_fwd(const __bf16* __restrict__ Qp, const __bf16* __restrict__ Kt,
              const __bf16* __restrict__ Vtt, __bf16* __restrict__ AOt) {
    constexpr int S = 2048, D = 1024;
    __shared__ __align__(16) __bf16 sK[3 * 4096];
    __shared__ __align__(16) __bf16 sV[3 * 4096];
    const int t = threadIdx.x, l = t & 63, w = t >> 6;
    const int c = l & 31, g = l >> 5;
    const int bid = blockIdx.x, slot = bid >> 3;
    const int bh = (slot >> 3) * 8 + (bid & 7);     // bh % 8 == XCD
    const int qb = slot & 7;
    const int b = bh >> 4, h = bh & 15;
    const int q0 = qb * 256;
    const __bf16* Kb = Kt + (size_t)bh * 131072;
    const __bf16* Vb = Vtt + (size_t)bh * 131072;

    // Q B-fragments: rows q0 + w*64 + qh*32 + c, dims ks*16 + g*8
    bf16x8 qf[2][4];
    #pragma unroll
    for (int qh = 0; qh < 2; qh++) {
        const __bf16* qp = Qp + (size_t)(b * S + q0 + w * 64 + qh * 32 + c) * D + h * 64;
        #pragma unroll
        for (int ks = 0; ks < 4; ks++)
            qf[qh][ks] = *(const bf16x8*)(qp + ks * 16 + g * 8);
    }
    const __bf16 one = (__bf16)1.0f;
    const bf16x8 ones = {one, one, one, one, one, one, one, one};
    asm volatile("s_waitcnt vmcnt(0)" ::: "memory");   // clean vmcnt before pipeline

#define AISSUE(ti_, buf_) do { \
    GLDS(Kb + (ti_) * 4096 + t * 8,        (char*)sK + (buf_) * 8192 + t * 16); \
    GLDS(Kb + (ti_) * 4096 + 2048 + t * 8, (char*)sK + (buf_) * 8192 + 4096 + t * 16); \
    GLDS(Vb + (ti_) * 4096 + t * 8,        (char*)sV + (buf_) * 8192 + t * 16); \
    GLDS(Vb + (ti_) * 4096 + 2048 + t * 8, (char*)sV + (buf_) * 8192 + 4096 + t * 16); \
} while (0)

    f32x16 acc[2][2];
    acc[0][0] = (f32x16){}; acc[0][1] = (f32x16){};
    acc[1][0] = (f32x16){}; acc[1][1] = (f32x16){};
    f32x16 accl[2];
    accl[0] = (f32x16){}; accl[1] = (f32x16){};

    AISSUE(0, 0);
    AISSUE(1, 1);
    int cur = 0;
    #pragma unroll 1
    for (int tile = 0; tile < 32; ++tile) {
        if (tile < 31) asm volatile("s_waitcnt vmcnt(4)" ::: "memory");
        else           asm volatile("s_waitcnt vmcnt(0)" ::: "memory");
        __builtin_amdgcn_s_barrier();
        __builtin_amdgcn_sched_barrier(0);
        if (tile + 2 < 32) AISSUE(tile + 2, cur >= 1 ? cur - 1 : 2);
        const __bf16* bK = sK + cur * 4096;
        const __bf16* bV = sV + cur * 4096;
        #pragma unroll
        for (int kt = 0; kt < 2; kt++) {
            bf16x8 kf[4];
            #pragma unroll
            for (int ks = 0; ks < 4; ks++)
                kf[ks] = *(const bf16x8*)(bK + ((2 * ks + g) * 64 + kt * 32 + c) * 8);
            bf16x8 vq0[2], vq1[2];
            #pragma unroll
            for (int ti = 0; ti < 2; ti++) {
                vq0[ti] = *(const bf16x8*)(bV + ((4 * kt + g) * 64 + ti * 32 + c) * 8);
                vq1[ti] = *(const bf16x8*)(bV + ((4 * kt + 2 + g) * 64 + ti * 32 + c) * 8);
            }
            #pragma unroll
            for (int qh = 0; qh < 2; qh++) {
                f32x16 St = {};
                __builtin_amdgcn_s_setprio(1);
                St = __builtin_amdgcn_mfma_f32_32x32x16_bf16(kf[0], qf[qh][0], St, 0, 0, 0);
                St = __builtin_amdgcn_mfma_f32_32x32x16_bf16(kf[1], qf[qh][1], St, 0, 0, 0);
                St = __builtin_amdgcn_mfma_f32_32x32x16_bf16(kf[2], qf[qh][2], St, 0, 0, 0);
                St = __builtin_amdgcn_mfma_f32_32x32x16_bf16(kf[3], qf[qh][3], St, 0, 0, 0);
                __builtin_amdgcn_s_setprio(0);
                #pragma unroll
                for (int r2 = 0; r2 < 16; r2++)
                    St[r2] = __builtin_amdgcn_exp2f(St[r2]);
                unsigned w0 = cvtpk_bf16(St[0], St[1]),   w1 = cvtpk_bf16(St[2], St[3]);
                unsigned w2 = cvtpk_bf16(St[4], St[5]),   w3 = cvtpk_bf16(St[6], St[7]);
                unsigned w4 = cvtpk_bf16(St[8], St[9]),   w5 = cvtpk_bf16(St[10], St[11]);
                unsigned w6 = cvtpk_bf16(St[12], St[13]), w7 = cvtpk_bf16(St[14], St[15]);
                pl32swap(w0, w2); pl32swap(w1, w3);
                pl32swap(w4, w6); pl32swap(w5, w7);
                bf16x8 pa0 = __builtin_bit_cast(bf16x8, (u32x4){w0, w1, w2, w3});
                bf16x8 pa1 = __builtin_bit_cast(bf16x8, (u32x4){w4, w5, w6, w7});
                __builtin_amdgcn_s_setprio(1);
                acc[qh][0] = __builtin_amdgcn_mfma_f32_32x32x16_bf16(pa0, vq0[0], acc[qh][0], 0, 0, 0);
                acc[qh][1] = __builtin_amdgcn_mfma_f32_32x32x16_bf16(pa0, vq0[1], acc[qh][1], 0, 0, 0);
                acc[qh][0] = __builtin_amdgcn_mfma_f32_32x32x16_bf16(pa1, vq1[0], acc[qh][0], 0, 0, 0);
                acc[qh][1] = __builtin_amdgcn_mfma_f32_32x32x16_bf16(pa1, vq1[1], acc[qh][1], 0, 0, 0);
                accl[qh] = __builtin_amdgcn_mfma_f32_32x32x16_bf16(pa0, ones, accl[qh], 0, 0, 0);
                accl[qh] = __builtin_amdgcn_mfma_f32_32x32x16_bf16(pa1, ones, accl[qh], 0, 0, 0);
                __builtin_amdgcn_s_setprio(0);
            }
        }
        cur = cur == 2 ? 0 : cur + 1;
    }
#undef AISSUE

    // write O in tiled-A layout for the final GEMM: m = b*2048+q, k = h*64 + ti*32 + c
    #pragma unroll
    for (int qh = 0; qh < 2; qh++)
        #pragma unroll
        for (int rq = 0; rq < 4; rq++)
            #pragma unroll
            for (int rr2 = 0; rr2 < 4; rr2++) {
                int reg = rq * 4 + rr2;
                int rloc = rr2 + 8 * rq + 4 * g;
                float rn = __builtin_amdgcn_rcpf(accl[qh][reg]);
                int qloc = w * 64 + qh * 32 + rloc;
                int mt = b * 16 + qb * 2 + (qloc >> 7);
                int mr = qloc & 127;
                size_t base = ((size_t)mt * 32 + h * 2) * 4096 + (size_t)(c >> 3) * 1024
                            + (size_t)mr * 8 + (c & 7);
                AOt[base] = (__bf16)(acc[qh][0][reg] * rn);
                AOt[base + 4096] = (__bf16)(acc[qh][1][reg] * rn);
            }
}

extern "C" void kernel_launch(void* const* d_in, const int* in_sizes, int n_in,
                              void* d_out, int out_size, void* d_ws, size_t ws_size,
                              hipStream_t stream) {
    const float* q  = (const float*)d_in[0];
    const float* k  = (const float*)d_in[1];
    const float* v  = (const float*)d_in[2];
    const float* Wq = (const float*)d_in[3];
    const float* bq = (const float*)d_in[4];
    const float* Wk = (const float*)d_in[5];
    const float* bk = (const float*)d_in[6];
    const float* Wv = (const float*)d_in[7];
    const float* bv = (const float*)d_in[8];
    const float* Wo = (const float*)d_in[9];
    const float* bo = (const float*)d_in[10];

    char* ws = (char*)d_ws;
    const size_t MiB = 1024 * 1024;
    __bf16* Atq = (__bf16*)(ws);             // tiled bf16 q (16MB); later reused as AOt
    __bf16* Atk = (__bf16*)(ws + 16 * MiB);
    __bf16* Atv = (__bf16*)(ws + 32 * MiB);
    __bf16* W2q = (__bf16*)(ws + 48 * MiB);
    __bf16* W2k = (__bf16*)(ws + 50 * MiB);
    __bf16* W2v = (__bf16*)(ws + 52 * MiB);
    __bf16* W2o = (__bf16*)(ws + 54 * MiB);
    __bf16* Qp  = (__bf16*)(ws + 56 * MiB);  // row-major bf16, pre-scaled
    __bf16* Kt  = (__bf16*)(ws + 72 * MiB);  // K tiled
    __bf16* Vtt = (__bf16*)(ws + 88 * MiB);  // V tiled
    __bf16* AOt = (__bf16*)(ws);             // attn out, tiled A (aliases Atq, dead)

    cvt_tile<<<dim3(64, 16, 3), 256, 0, stream>>>(q, k, v, Atq, Atk, Atv);

    wtrans2<<<dim3(16, 16, 4), 256, 0, stream>>>(Wq, Wk, Wv, Wo, W2q, W2k, W2v, W2o);

    // merged Q/K/V projection GEMMs (grid.y selects operand set; modes 1,2,3)
    gemm_tt<<<dim3(512, 3), 256, 0, stream>>>(Atq, Atk, Atv, W2q, W2k, W2v,
                                              bq, bk, bv, Qp, Kt, Vtt, 1);

    attn_fwd<<<512, 256, 0, stream>>>(Qp, Kt, Vtt, AOt);

    // output projection (mode 0: f32 row-major to d_out)
    gemm_tt<<<dim3(512, 1), 256, 0, stream>>>(AOt, AOt, AOt, W2o, W2o, W2o,
                                              bo, bo, bo, d_out, d_out, d_out, 0);
}

// Round 6
// 202.027 us; speedup vs baseline: 1.2336x; 1.0192x over previous
//
#include <hip/hip_runtime.h>

typedef __attribute__((ext_vector_type(8))) __bf16 bf16x8;
typedef __attribute__((ext_vector_type(4))) __bf16 bf16x4;
typedef __attribute__((ext_vector_type(4))) float f32x4;
typedef __attribute__((ext_vector_type(16))) float f32x16;
typedef __attribute__((ext_vector_type(4))) unsigned int u32x4;

#define GLDS(g, l) __builtin_amdgcn_global_load_lds( \
    (const __attribute__((address_space(1))) void*)(g), \
    (__attribute__((address_space(3))) void*)(l), 16, 0, 0)

__device__ __forceinline__ unsigned cvtpk_bf16(float lo, float hi) {
    unsigned r;
    asm("v_cvt_pk_bf16_f32 %0, %1, %2" : "=v"(r) : "v"(lo), "v"(hi));
    return r;
}
__device__ __forceinline__ void pl32swap(unsigned& a, unsigned& b) {
    asm("v_permlane32_swap_b32 %0, %1" : "+v"(a), "+v"(b));
}

// ---- fp32 [8192][1024] -> tiled bf16 A-layout [mt256][kt64][kc8][row256][8] ----
__global__ __launch_bounds__(256) void cvt_tile(const float* __restrict__ q,
                                                const float* __restrict__ k,
                                                const float* __restrict__ v,
                                                __bf16* __restrict__ qo,
                                                __bf16* __restrict__ ko,
                                                __bf16* __restrict__ vo) {
    const float* src = blockIdx.z == 0 ? q : blockIdx.z == 1 ? k : v;
    __bf16* dst = blockIdx.z == 0 ? qo : blockIdx.z == 1 ? ko : vo;
    __shared__ __align__(16) __bf16 sb[128 * 64];
    const int t = threadIdx.x;
    const int m0 = blockIdx.x * 128, kk0 = blockIdx.y * 64;
    #pragma unroll
    for (int i = 0; i < 4; i++) {
        int cid = i * 256 + t;
        int r = cid >> 3, cc = cid & 7;
        const float* p = src + (size_t)(m0 + r) * 1024 + kk0 + cc * 8;
        float4 a = *(const float4*)p;
        float4 b2 = *(const float4*)(p + 4);
        bf16x8 o;
        o[0] = (__bf16)a.x;  o[1] = (__bf16)a.y;  o[2] = (__bf16)a.z;  o[3] = (__bf16)a.w;
        o[4] = (__bf16)b2.x; o[5] = (__bf16)b2.y; o[6] = (__bf16)b2.z; o[7] = (__bf16)b2.w;
        *(bf16x8*)((char*)sb + r * 128 + ((cc ^ (r & 7)) << 4)) = o;
    }
    __syncthreads();
    const int mt = blockIdx.x >> 1, rowbase = (blockIdx.x & 1) * 128;
    #pragma unroll
    for (int i = 0; i < 4; i++) {
        int cid = i * 256 + t;
        int ch = cid >> 7, r = cid & 127;
        bf16x8 o = *(const bf16x8*)((const char*)sb + r * 128 + ((ch ^ (r & 7)) << 4));
        size_t off = (size_t)mt * 262144 + (size_t)blockIdx.y * 16384
                   + (size_t)ch * 2048 + (size_t)(rowbase + r) * 8;
        *(bf16x8*)(dst + off) = o;
    }
}

// ---- W [K][N] f32 -> tiled bf16 B-layout [nt128][kt64][kc8][col128][8] ----
__global__ __launch_bounds__(256) void wtrans2(const float* __restrict__ W0,
                                               const float* __restrict__ W1,
                                               const float* __restrict__ W2,
                                               const float* __restrict__ W3,
                                               __bf16* __restrict__ O0,
                                               __bf16* __restrict__ O1,
                                               __bf16* __restrict__ O2,
                                               __bf16* __restrict__ O3) {
    const int z = blockIdx.z;
    const float* W = z == 0 ? W0 : z == 1 ? W1 : z == 2 ? W2 : W3;
    __bf16* Wt2 = z == 0 ? O0 : z == 1 ? O1 : z == 2 ? O2 : O3;
    __shared__ float lw[64][65];
    const int kt = blockIdx.y * 64, nt = blockIdx.x * 64;
    const int t = threadIdx.x;
    const int r = t >> 4;
    const int c4 = (t & 15) * 4;
    #pragma unroll
    for (int rr = 0; rr < 64; rr += 16) {
        float4 vv = *(const float4*)&W[(size_t)(kt + r + rr) * 1024 + nt + c4];
        lw[r + rr][c4 + 0] = vv.x; lw[r + rr][c4 + 1] = vv.y;
        lw[r + rr][c4 + 2] = vv.z; lw[r + rr][c4 + 3] = vv.w;
    }
    __syncthreads();
    #pragma unroll
    for (int rr = 0; rr < 64; rr += 16) {
        int n = nt + r + rr;
        bf16x4 ov;
        #pragma unroll
        for (int i = 0; i < 4; i++) ov[i] = (__bf16)lw[c4 + i][r + rr];
        int kg = kt + c4;
        size_t off = (size_t)(n >> 7) * 131072 + (size_t)(kg >> 6) * 8192
                   + (size_t)((kg >> 3) & 7) * 1024 + (size_t)(n & 127) * 8 + (kg & 7);
        *(bf16x4*)&Wt2[off] = ov;
    }
}

// ---- GEMM 256x128, BK=64, 8 waves (4Mx2N), 32x32x16 MFMA, 3-tile-buffer,
//      2 phases/K-tile with counted vmcnt(6) (T3/T4), setprio (T5) ----
// modes: 0=f32 row-major, 1=bf16 row-major scaled (Q), 2=K-tiled, 3=V-tiled
template <int QKV>
__global__ __launch_bounds__(512, 2)
void gemm_ph(const __bf16* __restrict__ A0, const __bf16* __restrict__ A1,
             const __bf16* __restrict__ A2,
             const __bf16* __restrict__ B0, const __bf16* __restrict__ B1,
             const __bf16* __restrict__ B2,
             const float* __restrict__ bi0, const float* __restrict__ bi1,
             const float* __restrict__ bi2,
             void* __restrict__ C0, void* __restrict__ C1, void* __restrict__ C2) {
    __shared__ __align__(16) __bf16 sA[3 * 16384];   // 3 x 32KB
    __shared__ __align__(16) __bf16 sB[3 * 8192];    // 3 x 16KB
    const int t = threadIdx.x, l = t & 63;
    const int wv = t >> 6;
    const int wm = wv >> 1, wn = wv & 1;             // 4M x 2N waves
    const int y = blockIdx.y;
    const __bf16* At = QKV ? (y == 0 ? A0 : y == 1 ? A1 : A2) : A0;
    const __bf16* Bt = QKV ? (y == 0 ? B0 : y == 1 ? B1 : B2) : B0;
    const float* bias = QKV ? (y == 0 ? bi0 : y == 1 ? bi1 : bi2) : bi0;
    void* Cout        = QKV ? (y == 0 ? C0 : y == 1 ? C1 : C2) : C0;
    const int mode = QKV ? y + 1 : 0;

    const int bid = blockIdx.x;
    const int wgid = (bid & 7) * 32 + (bid >> 3);    // XCD-contiguous
    const int mt = wgid >> 3, ntg = wgid & 7;
    const __bf16* Ag = At + (size_t)mt * 262144;
    const __bf16* Bg = Bt + (size_t)ntg * 131072;

    // frag read byte offsets (A: [kc8][row256][16B], B: [kc8][col128][16B])
    const int aRow = ((wm * 64 + (l & 31)) << 4) + ((l >> 5) << 12);
    const int bRow = ((wn * 64 + (l & 31)) << 4) + ((l >> 5) << 11);

#define STG0(T_, nb_) do { \
    GLDS(Ag + (T_) * 16384 + t * 8,         (char*)sA + (nb_) * 32768 + t * 16); \
    GLDS(Ag + (T_) * 16384 + 4096 + t * 8,  (char*)sA + (nb_) * 32768 + 8192 + t * 16); \
    GLDS(Bg + (T_) * 8192 + t * 8,          (char*)sB + (nb_) * 16384 + t * 16); \
} while (0)
#define STG1(T_, nb_) do { \
    GLDS(Ag + (T_) * 16384 + 8192 + t * 8,  (char*)sA + (nb_) * 32768 + 16384 + t * 16); \
    GLDS(Ag + (T_) * 16384 + 12288 + t * 8, (char*)sA + (nb_) * 32768 + 24576 + t * 16); \
    GLDS(Bg + (T_) * 8192 + 4096 + t * 8,   (char*)sB + (nb_) * 16384 + 8192 + t * 16); \
} while (0)

    f32x16 acc[2][2];
    acc[0][0] = (f32x16){}; acc[0][1] = (f32x16){};
    acc[1][0] = (f32x16){}; acc[1][1] = (f32x16){};

    STG0(0, 0); STG1(0, 0);
    STG0(1, 1); STG1(1, 1);
    asm volatile("s_waitcnt vmcnt(6)" ::: "memory");   // tile 0 complete
    __builtin_amdgcn_s_barrier();

    int cur = 0;
    #pragma unroll 1
    for (int T = 0; T < 16; ++T) {
        const char* bA = (const char*)sA + cur * 32768;
        const char* bB = (const char*)sB + cur * 16384;
        const int nb = cur >= 1 ? cur - 1 : 2;         // (cur+2)%3, read-free
        #pragma unroll
        for (int ph = 0; ph < 2; ph++) {
            bf16x8 af[2][2], bfr[2][2];
            #pragma unroll
            for (int ks = 0; ks < 2; ks++) {
                int kst = ph * 2 + ks;
                #pragma unroll
                for (int r = 0; r < 2; r++) {
                    af[ks][r]  = *(const bf16x8*)(bA + kst * 8192 + aRow + r * 512);
                    bfr[ks][r] = *(const bf16x8*)(bB + kst * 4096 + bRow + r * 512);
                }
            }
            if (T + 2 < 16) {
                if (ph == 0) STG0(T + 2, nb); else STG1(T + 2, nb);
            }
            __builtin_amdgcn_s_barrier();
            asm volatile("s_waitcnt lgkmcnt(0)" ::: "memory");
            __builtin_amdgcn_sched_barrier(0);
            __builtin_amdgcn_s_setprio(1);
            #pragma unroll
            for (int ks = 0; ks < 2; ks++)
                #pragma unroll
                for (int r = 0; r < 2; r++)
                    #pragma unroll
                    for (int cc = 0; cc < 2; cc++)
                        acc[r][cc] = __builtin_amdgcn_mfma_f32_32x32x16_bf16(
                            af[ks][r], bfr[ks][cc], acc[r][cc], 0, 0, 0);
            __builtin_amdgcn_s_setprio(0);
            if (ph == 1) {
                if (T < 14) asm volatile("s_waitcnt vmcnt(6)" ::: "memory"); // T+1 ready
                else        asm volatile("s_waitcnt vmcnt(0)" ::: "memory");
            }
            __builtin_amdgcn_s_barrier();
        }
        cur = cur == 2 ? 0 : cur + 1;
    }
#undef STG0
#undef STG1

    const int m0 = mt * 256, col0 = ntg * 128;
    #pragma unroll
    for (int cc = 0; cc < 2; cc++) {
        int col = col0 + wn * 64 + cc * 32 + (l & 31);
        float bv = bias[col];
        #pragma unroll
        for (int r = 0; r < 2; r++) {
            #pragma unroll
            for (int reg = 0; reg < 16; reg++) {
                int row = m0 + wm * 64 + r * 32 + (reg & 3) + 8 * (reg >> 2) + 4 * (l >> 5);
                float vvv = acc[r][cc][reg] + bv;
                if (mode == 0) {
                    ((float*)Cout)[(size_t)row * 1024 + col] = vvv;
                } else if (mode == 1) {
                    ((__bf16*)Cout)[(size_t)row * 1024 + col] = (__bf16)(vvv * 0.18033688f);
                } else if (mode == 2) {
                    int b_ = row >> 11, s_ = row & 2047, h_ = col >> 6, hd_ = col & 63;
                    size_t off = ((size_t)(b_ * 16 + h_) * 32 + (s_ >> 6)) * 4096
                               + (size_t)(hd_ >> 3) * 512 + (s_ & 63) * 8 + (hd_ & 7);
                    ((__bf16*)Cout)[off] = (__bf16)vvv;
                } else {
                    int b_ = row >> 11, s_ = row & 2047, h_ = col >> 6, d_ = col & 63;
                    size_t off = ((size_t)(b_ * 16 + h_) * 32 + (s_ >> 6)) * 4096
                               + (size_t)((s_ & 63) >> 3) * 512 + (size_t)d_ * 8 + (s_ & 7);
                    ((__bf16*)Cout)[off] = (__bf16)vvv;
                }
            }
        }
    }
}

// ---- Flash attention (round-3 body, verified 77us) + new AOt epilogue ----
__global__ __launch_bounds__(256, 2)
void attn_fwd(const __bf16* __restrict__ Qp, const __bf16* __restrict__ Kt,
              const __bf16* __restrict__ Vtt, __bf16* __restrict__ AOt) {
    constexpr int S = 2048, D = 1024;
    __shared__ __align__(16) __bf16 sK[3 * 4096];
    __shared__ __align__(16) __bf16 sV[3 * 4096];
    __shared__ float sL[4][64];
    const int t = threadIdx.x, l = t & 63, w = t >> 6;
    const int c = l & 31, g = l >> 5;
    const int bid = blockIdx.x, slot = bid >> 3;
    const int bh = (slot >> 3) * 8 + (bid & 7);     // bh % 8 == XCD
    const int qb = slot & 7;
    const int b = bh >> 4, h = bh & 15;
    const int q0 = qb * 256;
    const __bf16* Kb = Kt + (size_t)bh * 131072;
    const __bf16* Vb = Vtt + (size_t)bh * 131072;

    bf16x8 qf[2][4];
    #pragma unroll
    for (int qh = 0; qh < 2; qh++) {
        const __bf16* qp = Qp + (size_t)(b * S + q0 + w * 64 + qh * 32 + c) * D + h * 64;
        #pragma unroll
        for (int ks = 0; ks < 4; ks++)
            qf[qh][ks] = *(const bf16x8*)(qp + ks * 16 + g * 8);
    }
    asm volatile("s_waitcnt vmcnt(0)" ::: "memory");

#define AISSUE(ti_, buf_) do { \
    GLDS(Kb + (ti_) * 4096 + t * 8,        (char*)sK + (buf_) * 8192 + t * 16); \
    GLDS(Kb + (ti_) * 4096 + 2048 + t * 8, (char*)sK + (buf_) * 8192 + 4096 + t * 16); \
    GLDS(Vb + (ti_) * 4096 + t * 8,        (char*)sV + (buf_) * 8192 + t * 16); \
    GLDS(Vb + (ti_) * 4096 + 2048 + t * 8, (char*)sV + (buf_) * 8192 + 4096 + t * 16); \
} while (0)

    f32x16 acc[2][2];
    acc[0][0] = (f32x16){}; acc[0][1] = (f32x16){};
    acc[1][0] = (f32x16){}; acc[1][1] = (f32x16){};
    float ls[2] = {0.f, 0.f};

    AISSUE(0, 0);
    AISSUE(1, 1);
    int cur = 0;
    #pragma unroll 1
    for (int tile = 0; tile < 32; ++tile) {
        if (tile < 31) asm volatile("s_waitcnt vmcnt(4)" ::: "memory");
        else           asm volatile("s_waitcnt vmcnt(0)" ::: "memory");
        __builtin_amdgcn_s_barrier();
        __builtin_amdgcn_sched_barrier(0);
        const __bf16* bK = sK + cur * 4096;
        const __bf16* bV = sV + cur * 4096;
        #pragma unroll
        for (int kt = 0; kt < 2; kt++) {
            bf16x8 kf[4];
            #pragma unroll
            for (int ks = 0; ks < 4; ks++)
                kf[ks] = *(const bf16x8*)(bK + ((2 * ks + g) * 64 + kt * 32 + c) * 8);
            bf16x8 vq0[2], vq1[2];
            #pragma unroll
            for (int ti = 0; ti < 2; ti++) {
                vq0[ti] = *(const bf16x8*)(bV + ((4 * kt + g) * 64 + ti * 32 + c) * 8);
                vq1[ti] = *(const bf16x8*)(bV + ((4 * kt + 2 + g) * 64 + ti * 32 + c) * 8);
            }
            #pragma unroll
            for (int qh = 0; qh < 2; qh++) {
                f32x16 St = {};
                St = __builtin_amdgcn_mfma_f32_32x32x16_bf16(kf[0], qf[qh][0], St, 0, 0, 0);
                St = __builtin_amdgcn_mfma_f32_32x32x16_bf16(kf[1], qf[qh][1], St, 0, 0, 0);
                St = __builtin_amdgcn_mfma_f32_32x32x16_bf16(kf[2], qf[qh][2], St, 0, 0, 0);
                St = __builtin_amdgcn_mfma_f32_32x32x16_bf16(kf[3], qf[qh][3], St, 0, 0, 0);
                #pragma unroll
                for (int r2 = 0; r2 < 16; r2++) {
                    float p = __builtin_amdgcn_exp2f(St[r2]);
                    ls[qh] += p;
                    St[r2] = p;
                }
                unsigned w0 = cvtpk_bf16(St[0], St[1]),   w1 = cvtpk_bf16(St[2], St[3]);
                unsigned w2 = cvtpk_bf16(St[4], St[5]),   w3 = cvtpk_bf16(St[6], St[7]);
                unsigned w4 = cvtpk_bf16(St[8], St[9]),   w5 = cvtpk_bf16(St[10], St[11]);
                unsigned w6 = cvtpk_bf16(St[12], St[13]), w7 = cvtpk_bf16(St[14], St[15]);
                pl32swap(w0, w2); pl32swap(w1, w3);
                pl32swap(w4, w6); pl32swap(w5, w7);
                bf16x8 pa0 = __builtin_bit_cast(bf16x8, (u32x4){w0, w1, w2, w3});
                bf16x8 pa1 = __builtin_bit_cast(bf16x8, (u32x4){w4, w5, w6, w7});
                acc[qh][0] = __builtin_amdgcn_mfma_f32_32x32x16_bf16(pa0, vq0[0], acc[qh][0], 0, 0, 0);
                acc[qh][1] = __builtin_amdgcn_mfma_f32_32x32x16_bf16(pa0, vq0[1], acc[qh][1], 0, 0, 0);
                acc[qh][0] = __builtin_amdgcn_mfma_f32_32x32x16_bf16(pa1, vq1[0], acc[qh][0], 0, 0, 0);
                acc[qh][1] = __builtin_amdgcn_mfma_f32_32x32x16_bf16(pa1, vq1[1], acc[qh][1], 0, 0, 0);
            }
        }
        if (tile + 2 < 32) AISSUE(tile + 2, cur >= 1 ? cur - 1 : 2);
        cur = cur == 2 ? 0 : cur + 1;
    }
#undef AISSUE

    float tt0 = ls[0] + __shfl_xor(ls[0], 32);
    float tt1 = ls[1] + __shfl_xor(ls[1], 32);
    if (l < 32) { sL[w][l] = 1.0f / tt0; sL[w][32 + l] = 1.0f / tt1; }
    __syncthreads();

    // write O in A-tiled layout [mt256][kt64][kc8][row256][8]; m=b*2048+q0+qloc, kcol=h*64+hi*32+c
    const int mt = b * 8 + qb;
    #pragma unroll
    for (int qh = 0; qh < 2; qh++)
        #pragma unroll
        for (int rq = 0; rq < 4; rq++)
            #pragma unroll
            for (int rr2 = 0; rr2 < 4; rr2++) {
                int reg = rq * 4 + rr2;
                int rloc = rr2 + 8 * rq + 4 * g;
                float rn = sL[w][qh * 32 + rloc];
                int qloc = w * 64 + qh * 32 + rloc;
                size_t base = (size_t)mt * 262144 + (size_t)h * 16384
                            + (size_t)(c >> 3) * 2048 + (size_t)qloc * 8 + (c & 7);
                AOt[base] = (__bf16)(acc[qh][0][reg] * rn);
                AOt[base + 8192] = (__bf16)(acc[qh][1][reg] * rn);   // hi=1: +4*2048
            }
}

extern "C" void kernel_launch(void* const* d_in, const int* in_sizes, int n_in,
                              void* d_out, int out_size, void* d_ws, size_t ws_size,
                              hipStream_t stream) {
    const float* q  = (const float*)d_in[0];
    const float* k  = (const float*)d_in[1];
    const float* v  = (const float*)d_in[2];
    const float* Wq = (const float*)d_in[3];
    const float* bq = (const float*)d_in[4];
    const float* Wk = (const float*)d_in[5];
    const float* bk = (const float*)d_in[6];
    const float* Wv = (const float*)d_in[7];
    const float* bv = (const float*)d_in[8];
    const float* Wo = (const float*)d_in[9];
    const float* bo = (const float*)d_in[10];

    char* ws = (char*)d_ws;
    const size_t MiB = 1024 * 1024;
    __bf16* Atq = (__bf16*)(ws);             // tiled bf16 q (16MB); later reused as AOt
    __bf16* Atk = (__bf16*)(ws + 16 * MiB);
    __bf16* Atv = (__bf16*)(ws + 32 * MiB);
    __bf16* W2q = (__bf16*)(ws + 48 * MiB);
    __bf16* W2k = (__bf16*)(ws + 50 * MiB);
    __bf16* W2v = (__bf16*)(ws + 52 * MiB);
    __bf16* W2o = (__bf16*)(ws + 54 * MiB);
    __bf16* Qp  = (__bf16*)(ws + 56 * MiB);  // row-major bf16, pre-scaled
    __bf16* Kt  = (__bf16*)(ws + 72 * MiB);  // K tiled (attn layout)
    __bf16* Vtt = (__bf16*)(ws + 88 * MiB);  // V tiled (attn layout)
    __bf16* AOt = (__bf16*)(ws);             // attn out, A-tiled (aliases Atq, dead)

    cvt_tile<<<dim3(64, 16, 3), 256, 0, stream>>>(q, k, v, Atq, Atk, Atv);

    wtrans2<<<dim3(16, 16, 4), 256, 0, stream>>>(Wq, Wk, Wv, Wo, W2q, W2k, W2v, W2o);

    // Q/K/V projections: grid.y selects operand set (modes 1,2,3)
    gemm_ph<1><<<dim3(256, 3), 512, 0, stream>>>(Atq, Atk, Atv, W2q, W2k, W2v,
                                                 bq, bk, bv, Qp, Kt, Vtt);

    attn_fwd<<<512, 256, 0, stream>>>(Qp, Kt, Vtt, AOt);

    // output projection (mode 0: f32 row-major to d_out)
    gemm_ph<0><<<dim3(256, 1), 512, 0, stream>>>(AOt, AOt, AOt, W2o, W2o, W2o,
                                                 bo, bo, bo, d_out, d_out, d_out);
}